// Round 4
// baseline (940.942 us; speedup 1.0000x reference)
//
#include <hip/hip_runtime.h>

#define T_ 7
#define H_ 64
#define W_ 64
#define KK_ 27
#define HW_ 4096
#define THW_ 28672
#define CO_OFF 54

// ---------------------------------------------------------------------------
// Weight transpose: dst[k][c][o] = (o < Co) ? src[o*1728 + c*27 + k] : 0
// (o padded to 64 with zeros so the GEMM can run a full 64x64 tile)
// ---------------------------------------------------------------------------
__global__ void prep_wt_kernel(const float* __restrict__ w_off0,
                               const float* __restrict__ w_off1,
                               const float* __restrict__ w0,
                               const float* __restrict__ w1,
                               float* __restrict__ wcT0, float* __restrict__ wcT1,
                               float* __restrict__ wdT0, float* __restrict__ wdT1) {
    int idx = blockIdx.x * 256 + threadIdx.x;      // 4 * 110592 total
    int which = idx / 110592;
    int r = idx - which * 110592;
    int k = r >> 12;
    int c = (r >> 6) & 63;
    int o = r & 63;
    const float* src;
    float* dst;
    int Co;
    switch (which) {
        case 0:  src = w_off0; dst = wcT0; Co = CO_OFF; break;
        case 1:  src = w_off1; dst = wcT1; Co = CO_OFF; break;
        case 2:  src = w0;     dst = wdT0; Co = 64;     break;
        default: src = w1;     dst = wdT1; Co = 64;     break;
    }
    float v = 0.f;
    if (o < Co) v = src[o * 1728 + c * 27 + k];
    dst[r] = v;
}

// ---------------------------------------------------------------------------
// Plain 3x3x3 conv (stride 1, pad 1) producing the 54 offset channels.
// One block per (t,h) row. K-loop over 27 taps; per tap stage shifted input
// row slab [64c][64w] + weight slice [64c][64o] in LDS, then 4x4-register GEMM.
// LDS GEMM reads are broadcast (4 unique weight addrs + 16 unique x addrs per
// wave per K-step) -> far under LDS BW ceiling -> VALU-issue-bound.
// ---------------------------------------------------------------------------
__global__ void __launch_bounds__(256) conv_off_kernel(
    const float* __restrict__ in, const float* __restrict__ wT,
    const float* __restrict__ bias, float* __restrict__ out) {
    __shared__ __align__(16) float lx[64][64];
    __shared__ __align__(16) float lwt[64][64];
    const int tid = threadIdx.x;
    const int bid = blockIdx.x;
    const int t = bid >> 6, h = bid & 63;
    const int w = tid & 63, cg = tid >> 6;
    const int o_blk = tid >> 4, w_blk = tid & 15;
    const int obase = o_blk * 4, wbase = w_blk * 4;

    float acc[4][4];
#pragma unroll
    for (int i = 0; i < 4; ++i)
#pragma unroll
        for (int j = 0; j < 4; ++j) acc[i][j] = 0.f;

    const float4* s4 = reinterpret_cast<const float4*>(wT) + tid;  // walks +1024/tap
    for (int k = 0; k < KK_; ++k) {
        const int kt = k / 9 - 1, kh = (k / 3) % 3 - 1, kw = k % 3 - 1;
        const int ts = t + kt, hs = h + kh, wsr = w + kw;
        const bool ok = ((unsigned)ts < 7u) & ((unsigned)hs < 64u) & ((unsigned)wsr < 64u);
        const float* src = in + (ts * HW_ + hs * W_ + wsr);
#pragma unroll
        for (int i = 0; i < 16; ++i) {
            const int c = cg * 16 + i;
            lx[c][w] = ok ? src[c * THW_] : 0.f;
        }
        float4* l4 = reinterpret_cast<float4*>(&lwt[0][0]);
#pragma unroll
        for (int i = 0; i < 4; ++i) l4[tid + i * 256] = s4[i * 256];
        s4 += 1024;
        __syncthreads();

#pragma unroll 8
        for (int c = 0; c < 64; ++c) {
            const float4 av = *reinterpret_cast<const float4*>(&lx[c][wbase]);
            const float4 wv = *reinterpret_cast<const float4*>(&lwt[c][obase]);
            const float a4[4] = {av.x, av.y, av.z, av.w};
            const float w4[4] = {wv.x, wv.y, wv.z, wv.w};
#pragma unroll
            for (int io = 0; io < 4; ++io)
#pragma unroll
                for (int iw = 0; iw < 4; ++iw)
                    acc[io][iw] = fmaf(w4[io], a4[iw], acc[io][iw]);
        }
        __syncthreads();
    }

    const int sb = t * HW_ + h * W_ + wbase;
#pragma unroll
    for (int io = 0; io < 4; ++io) {
        const int o = obase + io;
        if (o < CO_OFF) {
            const float b = bias[o];
            float* dst = out + o * THW_ + sb;
#pragma unroll
            for (int iw = 0; iw < 4; ++iw) dst[iw] = acc[io][iw] + b;
        }
    }
}

// ---------------------------------------------------------------------------
// Deformable conv (HW offsets only; integer temporal taps).
// Per tap: wave `corner` computes its bilinear corner index/weight for all 64
// w-positions (t/h/w bounds folded into zero weights, clamped indices), all
// threads gather the [64c][64w] sample slab into LDS, then the 4x4 GEMM.
// MODE 0: store leaky_relu(y).  MODE 1: store y + resid.
// ---------------------------------------------------------------------------
template <int MODE>
__global__ void __launch_bounds__(256) dcn_kernel(
    const float* __restrict__ in, const float* __restrict__ off,
    const float* __restrict__ wT, const float* __restrict__ resid,
    float* __restrict__ out) {
    __shared__ __align__(16) float la[64][64];
    __shared__ __align__(16) float lwt[64][64];
    __shared__ __align__(16) int   li[4][64];
    __shared__ __align__(16) float lf[4][64];
    const int tid = threadIdx.x;
    const int bid = blockIdx.x;
    const int t = bid >> 6, h = bid & 63;
    const int w = tid & 63, cg = tid >> 6;
    const int corner = tid >> 6;          // one bilinear corner per wave
    const int o_blk = tid >> 4, w_blk = tid & 15;
    const int obase = o_blk * 4, wbase = w_blk * 4;

    float acc[4][4];
#pragma unroll
    for (int i = 0; i < 4; ++i)
#pragma unroll
        for (int j = 0; j < 4; ++j) acc[i][j] = 0.f;

    const int sidx = t * HW_ + h * W_ + w;
    const float* offp = off + sidx;                                // walks +2*THW_/tap
    const float4* s4 = reinterpret_cast<const float4*>(wT) + tid;  // walks +1024/tap

    for (int k = 0; k < KK_; ++k) {
        const int kt = k / 9 - 1, kh = (k / 3) % 3 - 1, kw = k % 3 - 1;
        {
            const int ts = t + kt;
            const bool tok = (unsigned)ts < 7u;
            const int tcb = ts < 0 ? 0 : (ts > 6 ? 6 : ts);
            const float oh = offp[0];
            const float ow = offp[THW_];
            const float ph = (float)(h + kh) + oh;
            const float pw = (float)(w + kw) + ow;
            const float h0f = floorf(ph), w0f = floorf(pw);
            const float fh = ph - h0f, fw = pw - w0f;
            const int hi = (int)h0f + (corner >> 1);
            const int wi = (int)w0f + (corner & 1);
            const bool hk = (unsigned)hi < 64u, wk = (unsigned)wi < 64u;
            const int hc = hi < 0 ? 0 : (hi > 63 ? 63 : hi);
            const int wc = wi < 0 ? 0 : (wi > 63 ? 63 : wi);
            const float wgt = ((corner & 2) ? fh : 1.f - fh) *
                              ((corner & 1) ? fw : 1.f - fw);
            li[corner][w] = tcb * HW_ + hc * W_ + wc;
            lf[corner][w] = (tok && hk && wk) ? wgt : 0.f;
        }
        offp += 2 * THW_;
        float4* l4 = reinterpret_cast<float4*>(&lwt[0][0]);
#pragma unroll
        for (int i = 0; i < 4; ++i) l4[tid + i * 256] = s4[i * 256];
        s4 += 1024;
        __syncthreads();

        const int i0 = li[0][w], i1 = li[1][w], i2 = li[2][w], i3 = li[3][w];
        const float f0 = lf[0][w], f1 = lf[1][w], f2 = lf[2][w], f3 = lf[3][w];
#pragma unroll
        for (int i = 0; i < 16; ++i) {
            const int c = cg * 16 + i;
            const float* xc = in + c * THW_;
            la[c][w] = f0 * xc[i0] + f1 * xc[i1] + f2 * xc[i2] + f3 * xc[i3];
        }
        __syncthreads();

#pragma unroll 8
        for (int c = 0; c < 64; ++c) {
            const float4 av = *reinterpret_cast<const float4*>(&la[c][wbase]);
            const float4 wv = *reinterpret_cast<const float4*>(&lwt[c][obase]);
            const float a4[4] = {av.x, av.y, av.z, av.w};
            const float w4[4] = {wv.x, wv.y, wv.z, wv.w};
#pragma unroll
            for (int io = 0; io < 4; ++io)
#pragma unroll
                for (int iw = 0; iw < 4; ++iw)
                    acc[io][iw] = fmaf(w4[io], a4[iw], acc[io][iw]);
        }
        __syncthreads();
    }

    const int sb = t * HW_ + h * W_ + wbase;
#pragma unroll
    for (int io = 0; io < 4; ++io) {
        const int o = obase + io;
        float* dst = out + o * THW_ + sb;
        if (MODE == 0) {
#pragma unroll
            for (int iw = 0; iw < 4; ++iw) {
                const float v = acc[io][iw];
                dst[iw] = v > 0.f ? v : 0.1f * v;
            }
        } else {
            const float* r = resid + o * THW_ + sb;
#pragma unroll
            for (int iw = 0; iw < 4; ++iw) dst[iw] = acc[io][iw] + r[iw];
        }
    }
}

// ---------------------------------------------------------------------------
extern "C" void kernel_launch(void* const* d_in, const int* in_sizes, int n_in,
                              void* d_out, int out_size, void* d_ws, size_t ws_size,
                              hipStream_t stream) {
    (void)in_sizes; (void)n_in; (void)out_size; (void)ws_size;
    const float* x      = (const float*)d_in[0];
    const float* w_off0 = (const float*)d_in[1];
    const float* b_off0 = (const float*)d_in[2];
    const float* w0     = (const float*)d_in[3];
    const float* w_off1 = (const float*)d_in[4];
    const float* b_off1 = (const float*)d_in[5];
    const float* w1     = (const float*)d_in[6];
    float* out = (float*)d_out;

    float* ws = (float*)d_ws;
    float* off_buf = ws;                        // 54 * 28672
    float* y_buf   = off_buf + CO_OFF * THW_;   // 64 * 28672
    float* wcT0 = y_buf + 64 * THW_;            // 27*64*64 each
    float* wcT1 = wcT0 + 27 * 4096;
    float* wdT0 = wcT1 + 27 * 4096;
    float* wdT1 = wdT0 + 27 * 4096;

    prep_wt_kernel<<<1728, 256, 0, stream>>>(w_off0, w_off1, w0, w1,
                                             wcT0, wcT1, wdT0, wdT1);
    conv_off_kernel<<<448, 256, 0, stream>>>(x, wcT0, b_off0, off_buf);
    dcn_kernel<0><<<448, 256, 0, stream>>>(x, off_buf, wdT0, nullptr, y_buf);
    conv_off_kernel<<<448, 256, 0, stream>>>(y_buf, wcT1, b_off1, off_buf);
    dcn_kernel<1><<<448, 256, 0, stream>>>(y_buf, off_buf, wdT1, x, out);
}

// Round 5
// 626.517 us; speedup vs baseline: 1.5019x; 1.5019x over previous
//
#include <hip/hip_runtime.h>

#define T_ 7
#define H_ 64
#define W_ 64
#define KK_ 27
#define HW_ 4096
#define THW_ 28672
#define CO_OFF 54

// ---------------------------------------------------------------------------
// Weight transpose: dst[k][c][o] = (o < Co) ? src[o*1728 + c*27 + k] : 0
// ---------------------------------------------------------------------------
__global__ void prep_wt_kernel(const float* __restrict__ w_off0,
                               const float* __restrict__ w_off1,
                               const float* __restrict__ w0,
                               const float* __restrict__ w1,
                               float* __restrict__ wcT0, float* __restrict__ wcT1,
                               float* __restrict__ wdT0, float* __restrict__ wdT1) {
    int idx = blockIdx.x * 256 + threadIdx.x;      // 4 * 110592 total
    int which = idx / 110592;
    int r = idx - which * 110592;
    int k = r >> 12;
    int c = (r >> 6) & 63;
    int o = r & 63;
    const float* src;
    float* dst;
    int Co;
    switch (which) {
        case 0:  src = w_off0; dst = wcT0; Co = CO_OFF; break;
        case 1:  src = w_off1; dst = wcT1; Co = CO_OFF; break;
        case 2:  src = w0;     dst = wdT0; Co = 64;     break;
        default: src = w1;     dst = wdT1; Co = 64;     break;
    }
    float v = 0.f;
    if (o < Co) v = src[o * 1728 + c * 27 + k];
    dst[r] = v;
}

// ---------------------------------------------------------------------------
// Plain 3x3x3 conv, split-K across two 256-thread groups (512 thr / 8 waves).
// Group g handles c = g*32 .. g*32+31; partial accs reduced via LDS at end.
// 2 barriers per tap. Block = one (t,h) row of 64 w.
// ---------------------------------------------------------------------------
__global__ void __launch_bounds__(512) conv_off_kernel(
    const float* __restrict__ in, const float* __restrict__ wT,
    const float* __restrict__ bias, float* __restrict__ out) {
    __shared__ __align__(16) float la[64][64];    // 16 KB input slab (+ red buffer)
    __shared__ __align__(16) float lwt[64][64];   // 16 KB weight slice
    const int tid = threadIdx.x;
    const int bid = blockIdx.x;
    const int t = bid >> 6, h = bid & 63;
    const int w = tid & 63, cg = tid >> 6;        // cg 0..7 -> 8 channels each
    const int grp = tid >> 8;                     // split-K group 0/1
    const int l = tid & 255;
    const int obase = (l >> 4) * 4, wbase = (l & 15) * 4;
    const int cbase = grp * 32;

    float acc[4][4];
#pragma unroll
    for (int i = 0; i < 4; ++i)
#pragma unroll
        for (int j = 0; j < 4; ++j) acc[i][j] = 0.f;

    const float4* s4 = reinterpret_cast<const float4*>(wT) + tid;  // +1024/tap

    for (int k = 0; k < KK_; ++k) {
        const int kt = k / 9 - 1, kh = (k / 3) % 3 - 1, kw = k % 3 - 1;
        const int ts = t + kt, hs = h + kh, wsr = w + kw;
        const bool ok = ((unsigned)ts < 7u) & ((unsigned)hs < 64u) & ((unsigned)wsr < 64u);
        const float* src = in + (ts * HW_ + hs * W_ + wsr) + (cg * 8) * THW_;
#pragma unroll
        for (int i = 0; i < 8; ++i) {
            la[cg * 8 + i][w] = ok ? src[0] : 0.f;
            src += THW_;
        }
        float4* l4 = reinterpret_cast<float4*>(&lwt[0][0]);
        l4[tid] = s4[0];
        l4[tid + 512] = s4[512];
        s4 += 1024;
        __syncthreads();

#pragma unroll 8
        for (int c = 0; c < 32; ++c) {
            const float4 av = *reinterpret_cast<const float4*>(&la[cbase + c][wbase]);
            const float4 wv = *reinterpret_cast<const float4*>(&lwt[cbase + c][obase]);
            const float a4[4] = {av.x, av.y, av.z, av.w};
            const float w4[4] = {wv.x, wv.y, wv.z, wv.w};
#pragma unroll
            for (int io = 0; io < 4; ++io)
#pragma unroll
                for (int iw = 0; iw < 4; ++iw)
                    acc[io][iw] = fmaf(w4[io], a4[iw], acc[io][iw]);
        }
        __syncthreads();
    }

    // split-K reduction: group 1 writes partials, group 0 adds + stores
    float4* red = reinterpret_cast<float4*>(&la[0][0]);  // 1024 float4 slots
    if (grp == 1) {
#pragma unroll
        for (int io = 0; io < 4; ++io)
            red[l * 4 + io] = make_float4(acc[io][0], acc[io][1], acc[io][2], acc[io][3]);
    }
    __syncthreads();
    if (grp == 0) {
        const int sb = t * HW_ + h * W_ + wbase;
#pragma unroll
        for (int io = 0; io < 4; ++io) {
            const float4 r = red[l * 4 + io];
            acc[io][0] += r.x; acc[io][1] += r.y; acc[io][2] += r.z; acc[io][3] += r.w;
            const int o = obase + io;
            if (o < CO_OFF) {
                const float b = bias[o];
                float* dst = out + o * THW_ + sb;
#pragma unroll
                for (int iw = 0; iw < 4; ++iw) dst[iw] = acc[io][iw] + b;
            }
        }
    }
}

// ---------------------------------------------------------------------------
// Deformable conv, split-K 512-thread version. Each thread computes its own
// 4 bilinear corners in registers (t/h/w bounds folded into zero weights,
// clamped indices), gathers 8 channels into la, then the half-K 4x4 GEMM.
// Next-tap offsets are prefetched into registers (latency hides under GEMM).
// MODE 0: store leaky_relu(y).  MODE 1: store y + resid.
// ---------------------------------------------------------------------------
template <int MODE>
__global__ void __launch_bounds__(512) dcn_kernel(
    const float* __restrict__ in, const float* __restrict__ off,
    const float* __restrict__ wT, const float* __restrict__ resid,
    float* __restrict__ out) {
    __shared__ __align__(16) float la[64][64];    // 16 KB sample slab (+ red buffer)
    __shared__ __align__(16) float lwt[64][64];   // 16 KB weight slice
    const int tid = threadIdx.x;
    const int bid = blockIdx.x;
    const int t = bid >> 6, h = bid & 63;
    const int w = tid & 63, cg = tid >> 6;
    const int grp = tid >> 8;
    const int l = tid & 255;
    const int obase = (l >> 4) * 4, wbase = (l & 15) * 4;
    const int cbase = grp * 32;

    float acc[4][4];
#pragma unroll
    for (int i = 0; i < 4; ++i)
#pragma unroll
        for (int j = 0; j < 4; ++j) acc[i][j] = 0.f;

    const int sidx = t * HW_ + h * W_ + w;
    const float* offp = off + sidx;                                // +2*THW_/tap
    const float4* s4 = reinterpret_cast<const float4*>(wT) + tid;  // +1024/tap

    // prefetch tap-0 offsets
    float oh = offp[0], ow = offp[THW_];
    offp += 2 * THW_;

    for (int k = 0; k < KK_; ++k) {
        const int kt = k / 9 - 1, kh = (k / 3) % 3 - 1, kw = k % 3 - 1;
        // ---- per-thread bilinear corners (registers) ----
        const int ts = t + kt;
        const bool tok = (unsigned)ts < 7u;
        const int tcb = ts < 0 ? 0 : (ts > 6 ? 6 : ts);
        const float ph = (float)(h + kh) + oh;
        const float pw = (float)(w + kw) + ow;
        const float h0f = floorf(ph), w0f = floorf(pw);
        const float fh = ph - h0f, fw = pw - w0f;
        const int h0 = (int)h0f, w0i = (int)w0f;
        const int h1 = h0 + 1, w1i = w0i + 1;
        const bool h0k = (unsigned)h0 < 64u, h1k = (unsigned)h1 < 64u;
        const bool w0k = (unsigned)w0i < 64u, w1k = (unsigned)w1i < 64u;
        const int tb = tcb * HW_;
        const int h0c = (h0 < 0 ? 0 : (h0 > 63 ? 63 : h0)) * W_;
        const int h1c = (h1 < 0 ? 0 : (h1 > 63 ? 63 : h1)) * W_;
        const int w0c = w0i < 0 ? 0 : (w0i > 63 ? 63 : w0i);
        const int w1c = w1i < 0 ? 0 : (w1i > 63 ? 63 : w1i);
        const int i0 = tb + h0c + w0c, i1 = tb + h0c + w1c;
        const int i2 = tb + h1c + w0c, i3 = tb + h1c + w1c;
        const float f0 = (tok && h0k && w0k) ? (1.f - fh) * (1.f - fw) : 0.f;
        const float f1 = (tok && h0k && w1k) ? (1.f - fh) * fw : 0.f;
        const float f2 = (tok && h1k && w0k) ? fh * (1.f - fw) : 0.f;
        const float f3 = (tok && h1k && w1k) ? fh * fw : 0.f;

        // prefetch next-tap offsets (consumed next iteration)
        if (k + 1 < KK_) {
            oh = offp[0];
            ow = offp[THW_];
            offp += 2 * THW_;
        }

        // ---- stage weights (2 float4 / thread) ----
        float4* l4 = reinterpret_cast<float4*>(&lwt[0][0]);
        l4[tid] = s4[0];
        l4[tid + 512] = s4[512];
        s4 += 1024;

        // ---- gather 8 channels for this w ----
        const float* xc = in + (cg * 8) * THW_;
#pragma unroll
        for (int i = 0; i < 8; ++i) {
            la[cg * 8 + i][w] = f0 * xc[i0] + f1 * xc[i1] + f2 * xc[i2] + f3 * xc[i3];
            xc += THW_;
        }
        __syncthreads();

        // ---- half-K GEMM ----
#pragma unroll 8
        for (int c = 0; c < 32; ++c) {
            const float4 av = *reinterpret_cast<const float4*>(&la[cbase + c][wbase]);
            const float4 wv = *reinterpret_cast<const float4*>(&lwt[cbase + c][obase]);
            const float a4[4] = {av.x, av.y, av.z, av.w};
            const float w4[4] = {wv.x, wv.y, wv.z, wv.w};
#pragma unroll
            for (int io = 0; io < 4; ++io)
#pragma unroll
                for (int iw = 0; iw < 4; ++iw)
                    acc[io][iw] = fmaf(w4[io], a4[iw], acc[io][iw]);
        }
        __syncthreads();
    }

    // split-K reduction: group 1 writes partials, group 0 adds + stores
    float4* red = reinterpret_cast<float4*>(&la[0][0]);
    if (grp == 1) {
#pragma unroll
        for (int io = 0; io < 4; ++io)
            red[l * 4 + io] = make_float4(acc[io][0], acc[io][1], acc[io][2], acc[io][3]);
    }
    __syncthreads();
    if (grp == 0) {
        const int sb = t * HW_ + h * W_ + wbase;
#pragma unroll
        for (int io = 0; io < 4; ++io) {
            const float4 r = red[l * 4 + io];
            acc[io][0] += r.x; acc[io][1] += r.y; acc[io][2] += r.z; acc[io][3] += r.w;
            const int o = obase + io;
            float* dst = out + o * THW_ + sb;
            if (MODE == 0) {
#pragma unroll
                for (int iw = 0; iw < 4; ++iw) {
                    const float v = acc[io][iw];
                    dst[iw] = v > 0.f ? v : 0.1f * v;
                }
            } else {
                const float* r2 = resid + o * THW_ + sb;
#pragma unroll
                for (int iw = 0; iw < 4; ++iw) dst[iw] = acc[io][iw] + r2[iw];
            }
        }
    }
}

// ---------------------------------------------------------------------------
extern "C" void kernel_launch(void* const* d_in, const int* in_sizes, int n_in,
                              void* d_out, int out_size, void* d_ws, size_t ws_size,
                              hipStream_t stream) {
    (void)in_sizes; (void)n_in; (void)out_size; (void)ws_size;
    const float* x      = (const float*)d_in[0];
    const float* w_off0 = (const float*)d_in[1];
    const float* b_off0 = (const float*)d_in[2];
    const float* w0     = (const float*)d_in[3];
    const float* w_off1 = (const float*)d_in[4];
    const float* b_off1 = (const float*)d_in[5];
    const float* w1     = (const float*)d_in[6];
    float* out = (float*)d_out;

    float* ws = (float*)d_ws;
    float* off_buf = ws;                        // 54 * 28672
    float* y_buf   = off_buf + CO_OFF * THW_;   // 64 * 28672
    float* wcT0 = y_buf + 64 * THW_;            // 27*64*64 each
    float* wcT1 = wcT0 + 27 * 4096;
    float* wdT0 = wcT1 + 27 * 4096;
    float* wdT1 = wdT0 + 27 * 4096;

    prep_wt_kernel<<<1728, 256, 0, stream>>>(w_off0, w_off1, w0, w1,
                                             wcT0, wcT1, wdT0, wdT1);
    conv_off_kernel<<<448, 512, 0, stream>>>(x, wcT0, b_off0, off_buf);
    dcn_kernel<0><<<448, 512, 0, stream>>>(x, off_buf, wdT0, nullptr, y_buf);
    conv_off_kernel<<<448, 512, 0, stream>>>(y_buf, wcT1, b_off1, off_buf);
    dcn_kernel<1><<<448, 512, 0, stream>>>(y_buf, off_buf, wdT1, x, out);
}